// Round 8
// baseline (327.069 us; speedup 1.0000x reference)
//
#include <hip/hip_runtime.h>

// SNNDirectionDecoder, Round 7 (resubmit; prior round was an infra timeout):
// register-A fragments + W LDS double-buffer + counted-wait pipeline
// (one raw s_barrier per region, no vmem drain).
//
// Same numerics as R6 (fp16-split 3-product MFMA, scaled-by-16 LIF scan).
// Structural changes:
//  - A (x) fragments loaded straight to registers (2x dwordx4 per tile per
//    lane, 128B-contiguous per row-group), cvt'd to fp16 hi/lo in regs.
//    No x LDS traffic at all.
//  - W double-buffered in LDS (2x32KB, 2 blocks/CU). DMA for region r+1
//    issued at top of region r into the buffer whose readers finished
//    before the barrier we just passed.
//  - ONE raw __builtin_amdgcn_s_barrier() per region. The only vmcnt(0) is
//    the compiler's wait for x raw regs at the cvt, placed AFTER the MFMA
//    body (sched_barrier(0) fences pin the order), so DMA/L2 latency is
//    covered by ~48 MFMAs instead of being exposed at a barrier drain.
//  - TC=64: acc[4][4] (64 VGPR) + A frags 64 + raws 32 -> ~200 VGPR.
// Cross-wave safety: DMA(r+1) writes wbuf[(r+1)&1], last read in region r-1
// and those reads completed (lgkm, via MFMA consumption) before barrier_r.
// Dump+scan stays in the wave's OWN B-frag region of wbuf[r&1] (ks==7 ->
// r odd -> buffer 1), disjoint from the in-flight DMA (buffer 0).

#define B_   256
#define T_   500
#define I_   256
#define H_   512
#define C_   8

#define TC   64
#define BK   32
#define NKS  8                 // I_/BK
#define NCH  8                 // chunks of 64t covering 512 (t>=500 masked)
#define NR   (NCH * NKS)       // 64 regions

typedef __attribute__((ext_vector_type(8))) _Float16 half8;
typedef __attribute__((ext_vector_type(2))) __fp16 f16x2;
typedef __attribute__((ext_vector_type(4))) float f32x4;

typedef __attribute__((address_space(1))) const unsigned int as1_uint;
typedef __attribute__((address_space(3))) unsigned int as3_uint;

__device__ __forceinline__ void lds_dma16(const void* g, void* l) {
  __builtin_amdgcn_global_load_lds((as1_uint*)g, (as3_uint*)l, 16, 0, 0);
}

#define MFMA16(A, B, Cc) __builtin_amdgcn_mfma_f32_16x16x32_f16(A, B, Cc, 0, 0, 0)
#define SB0() __builtin_amdgcn_sched_barrier(0)

__global__ void init_out_kernel(const float* __restrict__ b2,
                                float* __restrict__ out) {
  int idx = blockIdx.x * 256 + threadIdx.x;
  if (idx < B_ * C_) out[idx] = (float)T_ * b2[idx & (C_ - 1)];
}

// W' = 16*W1 split to fp16 hi/lo. ws block (ks,half) = 32KB = [hi 16K][lo 16K];
// granule r = wv*256 + j*64 + c*16 + rr holds
// W'[half*256 + wv*64 + j*16 + rr][ks*32 + c*8 .. +8]  (same as R6).
__global__ void split_w1_kernel(const float* __restrict__ W1,
                                char* __restrict__ ws) {
  const int n = blockIdx.x * 256 + threadIdx.x;   // 16384 granules
  if (n >= H_ * NKS * 4) return;
  const int blk = n >> 10, r = n & 1023;
  const int ks = blk >> 1, hh = blk & 1;
  const int h = hh * 256 + (r >> 8) * 64 + ((r >> 6) & 3) * 16 + (r & 15);
  const int c = (r >> 4) & 3;
  const float* src = W1 + h * I_ + ks * BK + c * 8;
  union { half8 v; _Float16 e[8]; } hi, lo;
  #pragma unroll
  for (int e = 0; e < 8; ++e) {
    const float w = 16.0f * src[e];
    const _Float16 wh = (_Float16)w;
    hi.e[e] = wh;
    lo.e[e] = (_Float16)(w - (float)wh);
  }
  char* dst = ws + (size_t)blk * 32768 + (size_t)r * 16;
  *(half8*)dst = hi.v;
  *(half8*)(dst + 16384) = lo.v;
}

__device__ __forceinline__ void load_x8(const float* xb, int t, int col,
                                        float* a) {
  if (t < T_) {
    const float* p = xb + (size_t)t * I_ + col;
    const float4 v0 = *(const float4*)p;
    const float4 v1 = *(const float4*)(p + 4);
    a[0] = v0.x; a[1] = v0.y; a[2] = v0.z; a[3] = v0.w;
    a[4] = v1.x; a[5] = v1.y; a[6] = v1.z; a[7] = v1.w;
  } else {
    #pragma unroll
    for (int e = 0; e < 8; ++e) a[e] = 0.f;
  }
}

__device__ __forceinline__ void cvt_frag(const float* a, half8& hh, half8& ll) {
  union { half8 v; f16x2 p[4]; } H, L;
  #pragma unroll
  for (int k = 0; k < 4; ++k) {
    const f16x2 ha = __builtin_amdgcn_cvt_pkrtz(a[2 * k], a[2 * k + 1]);
    H.p[k] = ha;
    L.p[k] = __builtin_amdgcn_cvt_pkrtz(a[2 * k] - (float)ha[0],
                                        a[2 * k + 1] - (float)ha[1]);
  }
  hh = H.v;
  ll = L.v;
}

__global__ __launch_bounds__(256, 2) void snn_mfma4(
    const float* __restrict__ x, const char* __restrict__ ws,
    const float* __restrict__ b1, const float* __restrict__ W2,
    float* __restrict__ out) {
  __shared__ __align__(16) char smem[65536];   // W dbuf: 2 x 32KB

  const int tid = threadIdx.x;
  const int b = blockIdx.x, hf = blockIdx.y;
  const int l = tid & 63, wv = tid >> 6;
  const int xrow = l & 15;            // A-frag row (t within tile)
  const int xcolb = (l >> 4) * 8;     // A-frag k-chunk base

  const float* xb = x + (size_t)b * (T_ * I_);

  // per-j bias (acc h-col = j*16 + (l&15))
  float biasj[4];
  #pragma unroll
  for (int j = 0; j < 4; ++j)
    biasj[j] = 16.0f * b1[hf * 256 + wv * 64 + j * 16 + (l & 15)];

  float mreg = 0.f, cnt = 0.f;
  bool sp = false;

  f32x4 acc[4][4];
  #pragma unroll
  for (int i = 0; i < 4; ++i)
    #pragma unroll
    for (int j = 0; j < 4; ++j)
      acc[i][j] = (f32x4){biasj[j], biasj[j], biasj[j], biasj[j]};

  half8 ah[4], al[4];   // A fragments for the CURRENT region (loop-carried)

  // ---- prologue: DMA W(ks=0) -> buf0; x(region 0) -> regs -> frags
  {
    const char* wg = ws + (size_t)hf * 32768;
    #pragma unroll
    for (int q = 0; q < 8; ++q) {
      const int o = (q * 256 + tid) * 16;
      lds_dma16(wg + o, smem + o);
    }
    float raw[4][8];
    #pragma unroll
    for (int i = 0; i < 4; ++i) load_x8(xb, i * 16 + xrow, xcolb, raw[i]);
    #pragma unroll
    for (int i = 0; i < 4; ++i) cvt_frag(raw[i], ah[i], al[i]);
    // cvt's compiler-inserted vmcnt(0) also drains the DMA before the barrier
    SB0();
    __builtin_amdgcn_s_barrier();
  }

  #pragma unroll 1
  for (int r = 0; r < NR; ++r) {
    const char* wb = smem + (r & 1) * 32768;
    const bool stage = (r + 1 < NR);
    float raw[4][8];

    // 1) issue next region's W-DMA + x loads (covered by this region's MFMAs)
    if (stage) {
      const int r1 = r + 1;
      const char* wg = ws + (size_t)(((r1 & 7) << 1) + hf) * 32768;
      char* wdst = smem + (r1 & 1) * 32768;
      #pragma unroll
      for (int q = 0; q < 8; ++q) {
        const int o = (q * 256 + tid) * 16;
        lds_dma16(wg + o, wdst + o);
      }
      const int t1 = (r1 >> 3) * TC, c1 = (r1 & 7) * BK + xcolb;
      #pragma unroll
      for (int i = 0; i < 4; ++i)
        load_x8(xb, t1 + i * 16 + xrow, c1, raw[i]);
    }
    SB0();

    // 2) B frags (8 linear ds_read_b128) + 48 MFMA
    half8 bh[4], bl[4];
    #pragma unroll
    for (int j = 0; j < 4; ++j) {
      bh[j] = *(const half8*)(wb + (wv << 12) + (j << 10) + (l << 4));
      bl[j] = *(const half8*)(wb + 16384 + (wv << 12) + (j << 10) + (l << 4));
    }
    #pragma unroll
    for (int i = 0; i < 4; ++i)
      #pragma unroll
      for (int j = 0; j < 4; ++j) {
        acc[i][j] = MFMA16(ah[i], bh[j], acc[i][j]);
        acc[i][j] = MFMA16(al[i], bh[j], acc[i][j]);
        acc[i][j] = MFMA16(ah[i], bl[j], acc[i][j]);
      }
    SB0();

    // 3) chunk end: dump + scan in own B-region of wb (r odd -> buf1,
    //    disjoint from in-flight DMA into buf0)
    if ((r & 7) == 7) {
      char* dw = (char*)wb + (wv << 12);
      const int t0 = (r >> 3) * TC;
      #pragma unroll
      for (int p = 0; p < 4; ++p) {
        #pragma unroll
        for (int j = 0; j < 4; ++j)
          *(f32x4*)(dw + ((l >> 4) << 10) + (((j << 4) + (l & 15)) << 4)) =
              acc[p][j];
        const int tb = t0 + p * 16;
        #pragma unroll
        for (int g = 0; g < 4; ++g) {
          const float4 v = *(const float4*)(dw + (g << 10) + (l << 4));
          const float cv[4] = {v.x, v.y, v.z, v.w};
          #pragma unroll
          for (int e = 0; e < 4; ++e) {
            if (tb + g * 4 + e < T_) {
              const float rst = sp ? 16.0f : 0.0f;
              mreg = fmaf(0.9f, mreg, cv[e]) - rst;
              sp = mreg > 16.0f;
              if (sp) cnt += 1.0f;
            }
          }
        }
      }
      #pragma unroll
      for (int i = 0; i < 4; ++i)
        #pragma unroll
        for (int j = 0; j < 4; ++j)
          acc[i][j] = (f32x4){biasj[j], biasj[j], biasj[j], biasj[j]};
    }
    SB0();

    // 4) cvt next region's A frags (compiler vmcnt here -> drains DMA too,
    //    AFTER the MFMA body = full cover)
    if (stage) {
      #pragma unroll
      for (int i = 0; i < 4; ++i) cvt_frag(raw[i], ah[i], al[i]);
    }
    SB0();

    // 5) raw barrier, no vmem drain
    if (stage) __builtin_amdgcn_s_barrier();
  }

  // ---- projection: cnt[h = hf*256 + wv*64 + l] @ W2 -> out[b][c]
  const int hglob = hf * 256 + wv * 64 + l;
  #pragma unroll
  for (int c = 0; c < C_; ++c) {
    float p = cnt * W2[c * H_ + hglob];
    #pragma unroll
    for (int m = 32; m >= 1; m >>= 1) p += __shfl_xor(p, m, 64);
    if (l == 0) atomicAdd(&out[b * C_ + c], p);
  }
}

extern "C" void kernel_launch(void* const* d_in, const int* in_sizes, int n_in,
                              void* d_out, int out_size, void* d_ws,
                              size_t ws_size, hipStream_t stream) {
  (void)in_sizes; (void)n_in; (void)ws_size; (void)out_size;
  const float* x  = (const float*)d_in[0];
  const float* W1 = (const float*)d_in[1];
  const float* b1 = (const float*)d_in[2];
  const float* W2 = (const float*)d_in[3];
  const float* b2 = (const float*)d_in[4];
  float* out = (float*)d_out;
  char* ws = (char*)d_ws;   // 512 KB: 16 blocks x 32KB (ks x half, hi|lo)

  init_out_kernel<<<dim3((B_ * C_ + 255) / 256), dim3(256), 0, stream>>>(b2, out);
  split_w1_kernel<<<dim3(H_ * NKS * 4 / 256), dim3(256), 0, stream>>>(W1, ws);
  snn_mfma4<<<dim3(B_, 2), dim3(256), 0, stream>>>(x, ws, b1, W2, out);
}